// Round 1
// baseline (413.973 us; speedup 1.0000x reference)
//
#include <hip/hip_runtime.h>
#include <stdint.h>

typedef float  f32x4  __attribute__((ext_vector_type(4)));
typedef short  short8 __attribute__((ext_vector_type(8)));

#define DEV __device__ __forceinline__

DEV unsigned short f2bf(float x){
  union { float f; unsigned u; } v; v.f = x;
  unsigned r = v.u + 0x7fffu + ((v.u >> 16) & 1u);   // RNE
  return (unsigned short)(r >> 16);
}
DEV float bf2f(unsigned short u){
  union { unsigned u; float f; } v; v.u = ((unsigned)u) << 16;
  return v.f;
}
DEV float sig_(float x){ return 1.f/(1.f + __expf(-x)); }
DEV float tanh_(float x){ return 1.f - 2.f/(__expf(2.f*x) + 1.f); }

// ---------------------------------------------------------------------------
// Transpose fp32 [R][C] -> bf16 [C][R]; optional 8-block XOR swizzle on k-dim
// (so later kernels can copy global->LDS linearly and read with byte^((row&7)<<4))
// ---------------------------------------------------------------------------
template<bool SWZ>
__global__ void __launch_bounds__(256) transpose_bf16_k(const float* __restrict__ src,
    unsigned short* __restrict__ dst, int R, int C)
{
  __shared__ float tile[32][33];
  const int tx = threadIdx.x & 31, ty = threadIdx.x >> 5;
  const int c0 = blockIdx.x * 32, r0 = blockIdx.y * 32;
  #pragma unroll
  for (int m = 0; m < 4; ++m){
    int r = ty + m*8;
    tile[r][tx] = src[(size_t)(r0 + r) * C + (c0 + tx)];
  }
  __syncthreads();
  #pragma unroll
  for (int m = 0; m < 4; ++m){
    int cc = c0 + ty + m*8;
    int k  = r0 + tx;
    int k2 = SWZ ? (k ^ ((cc & 7) << 3)) : k;
    dst[(size_t)cc * R + k2] = f2bf(tile[tx][ty + m*8]);
  }
}

// ---------------------------------------------------------------------------
// out[3] = inputs[:,:,:,16:,:]   (pure linear copy per sample)
// ---------------------------------------------------------------------------
__global__ void __launch_bounds__(256) copy_out3_k(const float* __restrict__ in,
                                                   float* __restrict__ out3)
{
  int i = blockIdx.x * 256 + threadIdx.x;        // 98304 float4s
  int n = i / 24, q = i - n*24;
  f32x4 v = *(const f32x4*)(in + (size_t)n*128 + 32 + q*4);
  *(f32x4*)(out3 + (size_t)n*96 + q*4) = v;
}

// ---------------------------------------------------------------------------
// LSTM warm-up + autoregressive rollout.
// Block = 256 thr (4 waves = 4 gates i,f,g,o), 16 samples/block, 256 blocks.
// Wh fragments live in registers; h in swizzled bf16 LDS; c in fp32 registers.
// Writes: warm-up h -> concat[:, t*128+u] (pre-swizzled), preds -> out0.
// ---------------------------------------------------------------------------
__global__ void __launch_bounds__(256) lstm_k(
    const float* __restrict__ inputs, const float* __restrict__ Wi,
    const unsigned short* __restrict__ WhT, const float* __restrict__ bl,
    const float* __restrict__ Wp, const float* __restrict__ bp,
    unsigned short* __restrict__ concat, float* __restrict__ out0)
{
  __shared__ __align__(16) unsigned char hbuf[16*256];    // bf16 [16][128] swizzled
  __shared__ __align__(16) unsigned char zbuf[16*2048];   // f32  [16][512] swizzled
  __shared__ float xbuf[16][2];
  const int tid = threadIdx.x;
  const int lane = tid & 63, w = tid >> 6;                // wave = gate index
  const int n0 = blockIdx.x * 16;

  for (int i = tid; i < 16*256/4; i += 256) ((float*)hbuf)[i] = 0.f;

  // Wh fragments: wave w covers z-cols [w*128, w*128+128)
  short8 bfrag[8][4];
  {
    const int krow = (lane >> 4) * 8;
    #pragma unroll
    for (int nt = 0; nt < 8; ++nt){
      const unsigned short* p = WhT + (size_t)(w*128 + nt*16 + (lane & 15)) * 128;
      #pragma unroll
      for (int kt = 0; kt < 4; ++kt){
        bfrag[nt][kt] = *(const short8*)(p + kt*32 + krow);
      }
    }
  }
  float wi0[8], wi1[8], bb[8];
  #pragma unroll
  for (int nt = 0; nt < 8; ++nt){
    int col = w*128 + nt*16 + (lane & 15);
    wi0[nt] = Wi[col]; wi1[nt] = Wi[512 + col]; bb[nt] = bl[col];
  }
  float wpc[16];
  {
    int part = tid & 7, comp = (tid >> 3) & 1;
    #pragma unroll
    for (int j = 0; j < 16; ++j) wpc[j] = Wp[(part*16 + j)*2 + comp];
  }
  float cst[8];
  #pragma unroll
  for (int j = 0; j < 8; ++j) cst[j] = 0.f;
  const int es = tid >> 4, eu0 = (tid & 15) * 8;

  #pragma unroll 1
  for (int t = 0; t < 64; ++t){
    if (t < 16 && tid < 32){
      int s = tid >> 1, cmp = tid & 1;
      xbuf[s][cmp] = inputs[(size_t)(n0 + s)*128 + t*2 + cmp];
    }
    __syncthreads();

    // A fragments (h)
    short8 afr[4];
    {
      const int row = lane & 15;
      const int sw = (row & 7) << 4;
      #pragma unroll
      for (int kt = 0; kt < 4; ++kt){
        afr[kt] = *(const short8*)(hbuf + ((row*256 + kt*64 + (lane>>4)*16) ^ sw));
      }
    }
    float xs0[4], xs1[4];
    #pragma unroll
    for (int i = 0; i < 4; ++i){
      int s = (lane >> 4)*4 + i;
      xs0[i] = xbuf[s][0]; xs1[i] = xbuf[s][1];
    }
    f32x4 acc[8];
    #pragma unroll
    for (int nt = 0; nt < 8; ++nt){
      #pragma unroll
      for (int i = 0; i < 4; ++i){
        acc[nt][i] = xs0[i]*wi0[nt] + xs1[i]*wi1[nt] + bb[nt];
      }
    }
    #pragma unroll
    for (int kt = 0; kt < 4; ++kt){
      #pragma unroll
      for (int nt = 0; nt < 8; ++nt){
        acc[nt] = __builtin_amdgcn_mfma_f32_16x16x32_bf16(afr[kt], bfrag[nt][kt], acc[nt], 0, 0, 0);
      }
    }
    // scatter z (C/D layout: row=(lane>>4)*4+i, col=lane&15)
    #pragma unroll
    for (int nt = 0; nt < 8; ++nt){
      #pragma unroll
      for (int i = 0; i < 4; ++i){
        int s = (lane >> 4)*4 + i;
        int j = w*128 + nt*16 + (lane & 15);
        *(float*)(zbuf + ((s*2048 + j*4) ^ ((s & 7) << 4))) = acc[nt][i];
      }
    }
    __syncthreads();

    // gate elementwise: thread -> (sample es, units eu0..eu0+7)
    {
      const int sw = (es & 7) << 4;
      float zg4[4][8];
      #pragma unroll
      for (int g = 0; g < 4; ++g){
        #pragma unroll
        for (int q = 0; q < 2; ++q){
          f32x4 v = *(const f32x4*)(zbuf + ((es*2048 + (g*128 + eu0 + q*4)*4) ^ sw));
          zg4[g][q*4+0] = v[0]; zg4[g][q*4+1] = v[1];
          zg4[g][q*4+2] = v[2]; zg4[g][q*4+3] = v[3];
        }
      }
      short8 hv;
      #pragma unroll
      for (int j = 0; j < 8; ++j){
        float iv = sig_(zg4[0][j]);
        float fv = sig_(zg4[1][j]);
        float gv = tanh_(zg4[2][j]);
        float ov = sig_(zg4[3][j]);
        float c = fv*cst[j] + iv*gv;
        cst[j] = c;
        hv[j] = (short)f2bf(ov * tanh_(c));
      }
      *(short8*)(hbuf + ((es*256 + eu0*2) ^ sw)) = hv;
      if (t < 16){
        unsigned char* cp = (unsigned char*)concat + (size_t)(n0 + es)*28672
                          + ((unsigned)((t*128 + eu0)*2) ^ ((es & 7) << 4));
        *(short8*)cp = hv;
      }
    }
    __syncthreads();

    // pred = tanh(h@Wp + bp): 8 lanes per (sample, comp), shuffle-reduce
    if (t >= 15){
      const int s = tid >> 4, comp = (tid >> 3) & 1, part = tid & 7;
      const int sw = (s & 7) << 4;
      float sum = 0.f;
      #pragma unroll
      for (int j = 0; j < 16; ++j){
        int u = part*16 + j;
        sum += bf2f(*(const unsigned short*)(hbuf + ((s*256 + u*2) ^ sw))) * wpc[j];
      }
      sum += __shfl_xor(sum, 1);
      sum += __shfl_xor(sum, 2);
      sum += __shfl_xor(sum, 4);
      if (part == 0){
        float v = tanh_(sum + bp[comp]);
        xbuf[s][comp] = v;
        if (t >= 16) out0[(size_t)(n0 + s)*96 + (t - 16)*2 + comp] = v;
      }
    }
  }
}

// ---------------------------------------------------------------------------
// t1 = tanh(preds@W1+b1); t2 = tanh(t1@W2+b2) -> concat[:, 2048 + t*256 + c]
// Block: 256 thr, 8 row-tiles of 16 rows; W2^T fragments register-resident.
// ---------------------------------------------------------------------------
__global__ void __launch_bounds__(256) t1t2_k(
    const float* __restrict__ preds, const float* __restrict__ W1,
    const float* __restrict__ b1, const unsigned short* __restrict__ W2T,
    const float* __restrict__ b2, unsigned short* __restrict__ concat)
{
  __shared__ __align__(16) unsigned char t1buf[16*512];   // bf16 [16][256] swizzled
  const int tid = threadIdx.x, lane = tid & 63, w = tid >> 6;

  short8 bfrag[4][8];
  {
    const int krow = (lane >> 4) * 8;
    #pragma unroll
    for (int nt = 0; nt < 4; ++nt){
      const unsigned short* p = W2T + (size_t)(w*64 + nt*16 + (lane & 15)) * 256;
      #pragma unroll
      for (int kt = 0; kt < 8; ++kt){
        bfrag[nt][kt] = *(const short8*)(p + kt*32 + krow);
      }
    }
  }
  float b2c[4];
  #pragma unroll
  for (int nt = 0; nt < 4; ++nt) b2c[nt] = b2[w*64 + nt*16 + (lane & 15)];
  float w1a[16], w1b[16], b1c[16];
  {
    const int k0 = (tid & 15) * 16;
    #pragma unroll
    for (int j = 0; j < 16; ++j){
      w1a[j] = W1[k0 + j]; w1b[j] = W1[256 + k0 + j]; b1c[j] = b1[k0 + j];
    }
  }
  const int lr = tid >> 4, k0 = (tid & 15) * 16;

  #pragma unroll 1
  for (int rt = 0; rt < 8; ++rt){
    const int r0 = blockIdx.x * 128 + rt * 16;
    {
      const float p0 = preds[(size_t)(r0 + lr)*2 + 0];
      const float p1 = preds[(size_t)(r0 + lr)*2 + 1];
      const int sw = (lr & 7) << 4;
      #pragma unroll
      for (int h = 0; h < 2; ++h){
        short8 t1v;
        #pragma unroll
        for (int j = 0; j < 8; ++j){
          int jj = h*8 + j;
          t1v[j] = (short)f2bf(tanh_(p0*w1a[jj] + p1*w1b[jj] + b1c[jj]));
        }
        *(short8*)(t1buf + ((lr*512 + (k0 + h*8)*2) ^ sw)) = t1v;
      }
    }
    __syncthreads();
    f32x4 acc[4];
    #pragma unroll
    for (int nt = 0; nt < 4; ++nt) acc[nt] = (f32x4){0.f,0.f,0.f,0.f};
    {
      const int row = lane & 15;
      const int sw = (row & 7) << 4;
      #pragma unroll
      for (int kt = 0; kt < 8; ++kt){
        short8 a = *(const short8*)(t1buf + ((row*512 + (kt*32 + (lane>>4)*8)*2) ^ sw));
        #pragma unroll
        for (int nt = 0; nt < 4; ++nt){
          acc[nt] = __builtin_amdgcn_mfma_f32_16x16x32_bf16(a, bfrag[nt][kt], acc[nt], 0, 0, 0);
        }
      }
    }
    #pragma unroll
    for (int nt = 0; nt < 4; ++nt){
      const int col = w*64 + nt*16 + (lane & 15);
      #pragma unroll
      for (int i = 0; i < 4; ++i){
        int m = r0 + (lane >> 4)*4 + i;
        int n = m / 48, tt = m - n*48;
        unsigned short val = f2bf(tanh_(acc[nt][i] + b2c[nt]));
        *(unsigned short*)((unsigned char*)concat + (size_t)n*28672
            + ((unsigned)((2048 + tt*256 + col)*2) ^ ((n & 7) << 4))) = val;
      }
    }
    __syncthreads();
  }
}

// ---------------------------------------------------------------------------
// ev GEMM: [4096 x 14336] @ WcT -> split-K(8) partials [8][4096][256] fp32.
// concat & WcT are stored pre-swizzled, so staging is a linear coalesced copy
// and LDS reads use byte ^ ((row&7)<<4) conflict-free.
// ---------------------------------------------------------------------------
__global__ void __launch_bounds__(256) ev_k(
    const unsigned short* __restrict__ concat, const unsigned short* __restrict__ WcT,
    float* __restrict__ partials)
{
  __shared__ __align__(16) unsigned char Abuf[64*128];    // bf16 [64 rows][64 k]
  __shared__ __align__(16) unsigned char Bbuf[256*128];   // bf16 [256 cols][64 k]
  const int tid = threadIdx.x, lane = tid & 63, w = tid >> 6;
  const int n0 = blockIdx.x * 64;
  const int kbase = blockIdx.y * 1792;

  f32x4 acc[4][4];
  #pragma unroll
  for (int mt = 0; mt < 4; ++mt){
    #pragma unroll
    for (int nt = 0; nt < 4; ++nt) acc[mt][nt] = (f32x4){0.f,0.f,0.f,0.f};
  }

  const int aoff = tid * 32;
  const int arow = aoff >> 7;
  const unsigned char* asrc = (const unsigned char*)concat + (size_t)(n0 + arow)*28672 + (aoff & 127);
  const unsigned char* bsrc = (const unsigned char*)WcT + (size_t)tid*28672;

  #pragma unroll 1
  for (int ch = 0; ch < 28; ++ch){
    const int kk2 = (kbase + ch*64) * 2;
    short8 ar0 = *(const short8*)(asrc + kk2);
    short8 ar1 = *(const short8*)(asrc + kk2 + 16);
    short8 br[8];
    #pragma unroll
    for (int kb = 0; kb < 8; ++kb) br[kb] = *(const short8*)(bsrc + kk2 + kb*16);
    __syncthreads();
    *(short8*)(Abuf + aoff)      = ar0;
    *(short8*)(Abuf + aoff + 16) = ar1;
    #pragma unroll
    for (int kb = 0; kb < 8; ++kb) *(short8*)(Bbuf + tid*128 + kb*16) = br[kb];
    __syncthreads();
    #pragma unroll
    for (int kt = 0; kt < 2; ++kt){
      const int kby = kt*64 + (lane >> 4)*16;
      short8 afr[4], bfr[4];
      #pragma unroll
      for (int mt = 0; mt < 4; ++mt){
        int row = mt*16 + (lane & 15);
        afr[mt] = *(const short8*)(Abuf + ((row*128 + kby) ^ ((row & 7) << 4)));
      }
      #pragma unroll
      for (int nt = 0; nt < 4; ++nt){
        int col = w*64 + nt*16 + (lane & 15);
        bfr[nt] = *(const short8*)(Bbuf + ((col*128 + kby) ^ ((col & 7) << 4)));
      }
      #pragma unroll
      for (int mt = 0; mt < 4; ++mt){
        #pragma unroll
        for (int nt = 0; nt < 4; ++nt){
          acc[mt][nt] = __builtin_amdgcn_mfma_f32_16x16x32_bf16(afr[mt], bfr[nt], acc[mt][nt], 0, 0, 0);
        }
      }
    }
  }
  float* dst = partials + (size_t)blockIdx.y * (4096*256);
  #pragma unroll
  for (int mt = 0; mt < 4; ++mt){
    #pragma unroll
    for (int nt = 0; nt < 4; ++nt){
      #pragma unroll
      for (int i = 0; i < 4; ++i){
        int n = n0 + mt*16 + (lane >> 4)*4 + i;
        int col = w*64 + nt*16 + (lane & 15);
        dst[(size_t)n*256 + col] = acc[mt][nt][i];
      }
    }
  }
}

// ---------------------------------------------------------------------------
// Reduce split-K partials, ev = tanh(.+bc), then prob softmax + cost.
// Block = 16 samples; 16 lanes per sample; shuffle-reduce.
// ---------------------------------------------------------------------------
__global__ void __launch_bounds__(256) heads_k(
    const float* __restrict__ partials, const float* __restrict__ bc,
    const float* __restrict__ Wprob, const float* __restrict__ bprob,
    const float* __restrict__ Wasso, const float* __restrict__ basso,
    float* __restrict__ out1, float* __restrict__ out2)
{
  __shared__ float evs[16][257];
  const int tid = threadIdx.x;
  const int nl = tid >> 4, part = tid & 15;
  const int n = blockIdx.x * 16 + nl;
  #pragma unroll
  for (int q = 0; q < 4; ++q){
    const int c = part*16 + q*4;
    f32x4 s = {0.f,0.f,0.f,0.f};
    #pragma unroll
    for (int p = 0; p < 8; ++p){
      s += *(const f32x4*)(partials + (size_t)p*1048576 + (size_t)n*256 + c);
    }
    #pragma unroll
    for (int j = 0; j < 4; ++j) evs[nl][c + j] = tanh_(s[j] + bc[c + j]);
  }
  __syncthreads();
  float s0 = 0.f, s1 = 0.f, s2 = 0.f;
  #pragma unroll
  for (int j = 0; j < 16; ++j){
    int c = part*16 + j;
    float e = evs[nl][c];
    s0 += e * Wprob[c*2];
    s1 += e * Wprob[c*2 + 1];
    s2 += e * Wasso[c];
  }
  s0 += __shfl_xor(s0, 1); s1 += __shfl_xor(s1, 1); s2 += __shfl_xor(s2, 1);
  s0 += __shfl_xor(s0, 2); s1 += __shfl_xor(s1, 2); s2 += __shfl_xor(s2, 2);
  s0 += __shfl_xor(s0, 4); s1 += __shfl_xor(s1, 4); s2 += __shfl_xor(s2, 4);
  s0 += __shfl_xor(s0, 8); s1 += __shfl_xor(s1, 8); s2 += __shfl_xor(s2, 8);
  if (part == 0){
    float a0 = s0 + bprob[0], a1 = s1 + bprob[1];
    float m = fmaxf(a0, a1);
    float e0 = __expf(a0 - m), e1 = __expf(a1 - m);
    float inv = 1.f / (e0 + e1);
    out2[(size_t)n*96 + 0] = e0 * inv;
    out2[(size_t)n*96 + 1] = e1 * inv;
    out1[(size_t)n*96 + 0] = s2 + basso[0];
  }
}

// ---------------------------------------------------------------------------
extern "C" void kernel_launch(void* const* d_in, const int* in_sizes, int n_in,
                              void* d_out, int out_size, void* d_ws, size_t ws_size,
                              hipStream_t stream)
{
  (void)in_sizes; (void)n_in; (void)ws_size;
  const float* inputs = (const float*)d_in[0];
  const float* Wi     = (const float*)d_in[1];
  const float* Wh     = (const float*)d_in[2];
  const float* bl     = (const float*)d_in[3];
  const float* Wp     = (const float*)d_in[4];
  const float* bp     = (const float*)d_in[5];
  const float* W1     = (const float*)d_in[6];
  const float* b1     = (const float*)d_in[7];
  const float* W2     = (const float*)d_in[8];
  const float* b2     = (const float*)d_in[9];
  const float* Wc     = (const float*)d_in[10];
  const float* bc     = (const float*)d_in[11];
  const float* Wprob  = (const float*)d_in[12];
  const float* bprob  = (const float*)d_in[13];
  const float* Wasso  = (const float*)d_in[14];
  const float* basso  = (const float*)d_in[15];
  float* out = (float*)d_out;

  // workspace layout (needs ~152 MB)
  char* ws = (char*)d_ws;
  unsigned short* concat = (unsigned short*)ws;                 // [4096][14336] bf16 swizzled
  unsigned short* WhT    = (unsigned short*)(ws + 117440512);   // [512][128] bf16
  unsigned short* W2T    = (unsigned short*)(ws + 117571584);   // [256][256] bf16
  unsigned short* WcT    = (unsigned short*)(ws + 117702656);   // [256][14336] bf16 swizzled
  float*          parts  = (float*)(ws + 125042688);            // [8][4096][256] f32

  hipMemsetAsync(d_out, 0, (size_t)out_size * sizeof(float), stream);
  dim3 blk(256);
  transpose_bf16_k<false><<<dim3(16, 4),  blk, 0, stream>>>(Wh, WhT, 128, 512);
  transpose_bf16_k<false><<<dim3(8, 8),   blk, 0, stream>>>(W2, W2T, 256, 256);
  transpose_bf16_k<true ><<<dim3(8, 448), blk, 0, stream>>>(Wc, WcT, 14336, 256);
  copy_out3_k<<<384, blk, 0, stream>>>(inputs, out + 3*393216);
  lstm_k<<<256, blk, 0, stream>>>(inputs, Wi, WhT, bl, Wp, bp, concat, out);
  t1t2_k<<<1536, blk, 0, stream>>>(out, W1, b1, W2T, b2, concat);
  ev_k<<<dim3(64, 8), blk, 0, stream>>>(concat, WcT, parts);
  heads_k<<<256, blk, 0, stream>>>(parts, bc, Wprob, bprob, Wasso, basso,
                                   out + 393216, out + 2*393216);
}

// Round 2
// 371.133 us; speedup vs baseline: 1.1154x; 1.1154x over previous
//
#include <hip/hip_runtime.h>
#include <stdint.h>

typedef float  f32x4  __attribute__((ext_vector_type(4)));
typedef short  short8 __attribute__((ext_vector_type(8)));

#define DEV __device__ __forceinline__

DEV unsigned short f2bf(float x){
  union { float f; unsigned u; } v; v.f = x;
  unsigned r = v.u + 0x7fffu + ((v.u >> 16) & 1u);   // RNE
  return (unsigned short)(r >> 16);
}
DEV float bf2f(unsigned short u){
  union { unsigned u; float f; } v; v.u = ((unsigned)u) << 16;
  return v.f;
}
DEV float sig_(float x){ return 1.f/(1.f + __expf(-x)); }
DEV float tanh_(float x){ return 1.f - 2.f/(__expf(2.f*x) + 1.f); }

// ---------------------------------------------------------------------------
// Transpose fp32 [R][C] -> bf16 [C][R]; optional 8-block XOR swizzle on k-dim
// ---------------------------------------------------------------------------
template<bool SWZ>
__global__ void __launch_bounds__(256) transpose_bf16_k(const float* __restrict__ src,
    unsigned short* __restrict__ dst, int R, int C)
{
  __shared__ float tile[32][33];
  const int tx = threadIdx.x & 31, ty = threadIdx.x >> 5;
  const int c0 = blockIdx.x * 32, r0 = blockIdx.y * 32;
  #pragma unroll
  for (int m = 0; m < 4; ++m){
    int r = ty + m*8;
    tile[r][tx] = src[(size_t)(r0 + r) * C + (c0 + tx)];
  }
  __syncthreads();
  #pragma unroll
  for (int m = 0; m < 4; ++m){
    int cc = c0 + ty + m*8;
    int k  = r0 + tx;
    int k2 = SWZ ? (k ^ ((cc & 7) << 3)) : k;
    dst[(size_t)cc * R + k2] = f2bf(tile[tx][ty + m*8]);
  }
}

// ---------------------------------------------------------------------------
// out[3] = inputs[:,:,:,16:,:]
// ---------------------------------------------------------------------------
__global__ void __launch_bounds__(256) copy_out3_k(const float* __restrict__ in,
                                                   float* __restrict__ out3)
{
  int i = blockIdx.x * 256 + threadIdx.x;        // 98304 float4s
  int n = i / 24, q = i - n*24;
  f32x4 v = *(const f32x4*)(in + (size_t)n*128 + 32 + q*4);
  *(f32x4*)(out3 + (size_t)n*96 + q*4) = v;
}

// ---------------------------------------------------------------------------
// LSTM warm-up + autoregressive rollout. v2:
//  - 512 threads (8 waves), 16 samples/block, 256 blocks -> 2 waves/SIMD.
//  - wave w owns unit slice [w*16, w*16+16) x ALL 4 gates -> gate combine is
//    fully in-register (no zbuf, 2 barriers/step instead of 3).
//  - pred(t) partials via shfl butterfly while h is in regs; cross-wave finish
//    by wave 0 at start of step t+1, overlapped with the 16 in-flight MFMAs
//    (x*Wi is FMA'd into acc after the MFMA chain).
//  - warm-up x preloaded to LDS; warm-up h -> concat is a raw linear copy
//    (hbuf swizzle == concat swizzle for the same sample index).
// ---------------------------------------------------------------------------
__global__ void __launch_bounds__(512, 2) lstm_k(
    const float* __restrict__ inputs, const float* __restrict__ Wi,
    const unsigned short* __restrict__ WhT, const float* __restrict__ bl,
    const float* __restrict__ Wp, const float* __restrict__ bp,
    unsigned short* __restrict__ concat, float* __restrict__ out0)
{
  __shared__ __align__(16) unsigned char hbuf[16*256];   // bf16 [16][128] swizzled
  __shared__ float xwu[16][32];                          // warm-up inputs
  __shared__ float part[8][17][2];                       // pred partials (padded)
  __shared__ float xbuf[16][2];                          // AR input broadcast
  const int tid = threadIdx.x, lane = tid & 63, w = tid >> 6;
  const int n0 = blockIdx.x * 16;
  const int u = w*16 + (lane & 15);          // unit owned by this thread
  const int rbase = (lane >> 4) * 4;         // rows rbase..rbase+3

  { // preload warm-up inputs (coalesced)
    int s = tid >> 5, e = tid & 31;
    xwu[s][e] = inputs[(size_t)(n0 + s)*128 + e];
  }
  // B fragments: gate g, col = g*128 + u   (WhT = [512 cols][128 k])
  short8 bfrag[4][4];
  #pragma unroll
  for (int g = 0; g < 4; ++g){
    const unsigned short* p = WhT + (size_t)(g*128 + u) * 128;
    #pragma unroll
    for (int kt = 0; kt < 4; ++kt)
      bfrag[g][kt] = *(const short8*)(p + kt*32 + (lane >> 4)*8);
  }
  float wi0[4], wi1[4], bb[4];
  #pragma unroll
  for (int g = 0; g < 4; ++g){
    int col = g*128 + u;
    wi0[g] = Wi[col]; wi1[g] = Wi[512 + col]; bb[g] = bl[col];
  }
  const float wp0 = Wp[u*2], wp1 = Wp[u*2 + 1];
  float cst[4] = {0.f, 0.f, 0.f, 0.f};
  __syncthreads();

  #pragma unroll 1
  for (int t = 0; t < 64; ++t){
    f32x4 acc[4];
    #pragma unroll
    for (int g = 0; g < 4; ++g) acc[g] = (f32x4){bb[g], bb[g], bb[g], bb[g]};
    if (t > 0){
      short8 afr[4];
      const int row = lane & 15;
      const int sw = (row & 7) << 4;
      #pragma unroll
      for (int kt = 0; kt < 4; ++kt)
        afr[kt] = *(const short8*)(hbuf + ((row*256 + kt*64 + (lane>>4)*16) ^ sw));
      #pragma unroll
      for (int kt = 0; kt < 4; ++kt){
        #pragma unroll
        for (int g = 0; g < 4; ++g)
          acc[g] = __builtin_amdgcn_mfma_f32_16x16x32_bf16(afr[kt], bfrag[g][kt], acc[g], 0, 0, 0);
      }
    }
    // wave 0: finish pred(t-1) while MFMAs are in flight
    if (t >= 16 && tid < 64){
      int s = tid >> 2, comp = (tid >> 1) & 1, half = tid & 1;
      float sum = 0.f;
      #pragma unroll
      for (int p = 0; p < 4; ++p) sum += part[half*4 + p][s][comp];
      sum += __shfl_xor(sum, 1);
      if (half == 0){
        float v = tanh_(sum + bp[comp]);
        xbuf[s][comp] = v;
        if (t >= 17) out0[(size_t)(n0 + s)*96 + (t - 17)*2 + comp] = v;
      }
    }
    __syncthreads();

    float xs0[4], xs1[4];
    #pragma unroll
    for (int i = 0; i < 4; ++i){
      int s = rbase + i;
      if (t < 16){ xs0[i] = xwu[s][t*2]; xs1[i] = xwu[s][t*2 + 1]; }
      else       { xs0[i] = xbuf[s][0];  xs1[i] = xbuf[s][1]; }
    }
    float hf[4];
    #pragma unroll
    for (int i = 0; i < 4; ++i){
      float z0 = acc[0][i] + xs0[i]*wi0[0] + xs1[i]*wi1[0];
      float z1 = acc[1][i] + xs0[i]*wi0[1] + xs1[i]*wi1[1];
      float z2 = acc[2][i] + xs0[i]*wi0[2] + xs1[i]*wi1[2];
      float z3 = acc[3][i] + xs0[i]*wi0[3] + xs1[i]*wi1[3];
      float iv = sig_(z0), fv = sig_(z1), gv = tanh_(z2), ov = sig_(z3);
      float c = fv*cst[i] + iv*gv;
      cst[i] = c;
      hf[i] = ov * tanh_(c);
    }
    #pragma unroll
    for (int i = 0; i < 4; ++i){
      int r = rbase + i;
      *(unsigned short*)(hbuf + ((r*256 + u*2) ^ ((r & 7) << 4))) = f2bf(hf[i]);
    }
    if (t >= 15){  // pred partials from in-register h
      float hp0[4], hp1[4];
      #pragma unroll
      for (int i = 0; i < 4; ++i){ hp0[i] = hf[i]*wp0; hp1[i] = hf[i]*wp1; }
      #pragma unroll
      for (int m = 1; m < 16; m <<= 1){
        #pragma unroll
        for (int i = 0; i < 4; ++i){
          hp0[i] += __shfl_xor(hp0[i], m);
          hp1[i] += __shfl_xor(hp1[i], m);
        }
      }
      if ((lane & 15) == 0){
        #pragma unroll
        for (int i = 0; i < 4; ++i){
          part[w][rbase + i][0] = hp0[i];
          part[w][rbase + i][1] = hp1[i];
        }
      }
    }
    __syncthreads();
    if (t < 16 && tid < 256){
      // raw linear copy hbuf -> concat warm-up slice (swizzles coincide)
      int s = tid >> 4, o = (tid & 15) * 16;
      *(short8*)((unsigned char*)concat + (size_t)(n0 + s)*28672 + t*256 + o)
          = *(const short8*)(hbuf + s*256 + o);
    }
  }
  // epilogue: pred(63) -> out0 slot 47
  if (tid < 64){
    int s = tid >> 2, comp = (tid >> 1) & 1, half = tid & 1;
    float sum = 0.f;
    #pragma unroll
    for (int p = 0; p < 4; ++p) sum += part[half*4 + p][s][comp];
    sum += __shfl_xor(sum, 1);
    if (half == 0)
      out0[(size_t)(n0 + s)*96 + 47*2 + comp] = tanh_(sum + bp[comp]);
  }
}

// ---------------------------------------------------------------------------
// t1 = tanh(preds@W1+b1); t2 = tanh(t1@W2+b2) -> concat[:, 2048 + t*256 + c]
// ---------------------------------------------------------------------------
__global__ void __launch_bounds__(256) t1t2_k(
    const float* __restrict__ preds, const float* __restrict__ W1,
    const float* __restrict__ b1, const unsigned short* __restrict__ W2T,
    const float* __restrict__ b2, unsigned short* __restrict__ concat)
{
  __shared__ __align__(16) unsigned char t1buf[16*512];   // bf16 [16][256] swizzled
  const int tid = threadIdx.x, lane = tid & 63, w = tid >> 6;

  short8 bfrag[4][8];
  {
    const int krow = (lane >> 4) * 8;
    #pragma unroll
    for (int nt = 0; nt < 4; ++nt){
      const unsigned short* p = W2T + (size_t)(w*64 + nt*16 + (lane & 15)) * 256;
      #pragma unroll
      for (int kt = 0; kt < 8; ++kt){
        bfrag[nt][kt] = *(const short8*)(p + kt*32 + krow);
      }
    }
  }
  float b2c[4];
  #pragma unroll
  for (int nt = 0; nt < 4; ++nt) b2c[nt] = b2[w*64 + nt*16 + (lane & 15)];
  float w1a[16], w1b[16], b1c[16];
  {
    const int k0 = (tid & 15) * 16;
    #pragma unroll
    for (int j = 0; j < 16; ++j){
      w1a[j] = W1[k0 + j]; w1b[j] = W1[256 + k0 + j]; b1c[j] = b1[k0 + j];
    }
  }
  const int lr = tid >> 4, k0 = (tid & 15) * 16;

  #pragma unroll 1
  for (int rt = 0; rt < 8; ++rt){
    const int r0 = blockIdx.x * 128 + rt * 16;
    {
      const float p0 = preds[(size_t)(r0 + lr)*2 + 0];
      const float p1 = preds[(size_t)(r0 + lr)*2 + 1];
      const int sw = (lr & 7) << 4;
      #pragma unroll
      for (int h = 0; h < 2; ++h){
        short8 t1v;
        #pragma unroll
        for (int j = 0; j < 8; ++j){
          int jj = h*8 + j;
          t1v[j] = (short)f2bf(tanh_(p0*w1a[jj] + p1*w1b[jj] + b1c[jj]));
        }
        *(short8*)(t1buf + ((lr*512 + (k0 + h*8)*2) ^ sw)) = t1v;
      }
    }
    __syncthreads();
    f32x4 acc[4];
    #pragma unroll
    for (int nt = 0; nt < 4; ++nt) acc[nt] = (f32x4){0.f,0.f,0.f,0.f};
    {
      const int row = lane & 15;
      const int sw = (row & 7) << 4;
      #pragma unroll
      for (int kt = 0; kt < 8; ++kt){
        short8 a = *(const short8*)(t1buf + ((row*512 + (kt*32 + (lane>>4)*8)*2) ^ sw));
        #pragma unroll
        for (int nt = 0; nt < 4; ++nt){
          acc[nt] = __builtin_amdgcn_mfma_f32_16x16x32_bf16(a, bfrag[nt][kt], acc[nt], 0, 0, 0);
        }
      }
    }
    #pragma unroll
    for (int nt = 0; nt < 4; ++nt){
      const int col = w*64 + nt*16 + (lane & 15);
      #pragma unroll
      for (int i = 0; i < 4; ++i){
        int m = r0 + (lane >> 4)*4 + i;
        int n = m / 48, tt = m - n*48;
        unsigned short val = f2bf(tanh_(acc[nt][i] + b2c[nt]));
        *(unsigned short*)((unsigned char*)concat + (size_t)n*28672
            + ((unsigned)((2048 + tt*256 + col)*2) ^ ((n & 7) << 4))) = val;
      }
    }
    __syncthreads();
  }
}

// ---------------------------------------------------------------------------
// ev GEMM: [4096 x 14336] @ WcT -> split-K(8) partials [8][4096][256] fp32.
// ---------------------------------------------------------------------------
__global__ void __launch_bounds__(256) ev_k(
    const unsigned short* __restrict__ concat, const unsigned short* __restrict__ WcT,
    float* __restrict__ partials)
{
  __shared__ __align__(16) unsigned char Abuf[64*128];    // bf16 [64 rows][64 k]
  __shared__ __align__(16) unsigned char Bbuf[256*128];   // bf16 [256 cols][64 k]
  const int tid = threadIdx.x, lane = tid & 63, w = tid >> 6;
  const int n0 = blockIdx.x * 64;
  const int kbase = blockIdx.y * 1792;

  f32x4 acc[4][4];
  #pragma unroll
  for (int mt = 0; mt < 4; ++mt){
    #pragma unroll
    for (int nt = 0; nt < 4; ++nt) acc[mt][nt] = (f32x4){0.f,0.f,0.f,0.f};
  }

  const int aoff = tid * 32;
  const int arow = aoff >> 7;
  const unsigned char* asrc = (const unsigned char*)concat + (size_t)(n0 + arow)*28672 + (aoff & 127);
  const unsigned char* bsrc = (const unsigned char*)WcT + (size_t)tid*28672;

  #pragma unroll 1
  for (int ch = 0; ch < 28; ++ch){
    const int kk2 = (kbase + ch*64) * 2;
    short8 ar0 = *(const short8*)(asrc + kk2);
    short8 ar1 = *(const short8*)(asrc + kk2 + 16);
    short8 br[8];
    #pragma unroll
    for (int kb = 0; kb < 8; ++kb) br[kb] = *(const short8*)(bsrc + kk2 + kb*16);
    __syncthreads();
    *(short8*)(Abuf + aoff)      = ar0;
    *(short8*)(Abuf + aoff + 16) = ar1;
    #pragma unroll
    for (int kb = 0; kb < 8; ++kb) *(short8*)(Bbuf + tid*128 + kb*16) = br[kb];
    __syncthreads();
    #pragma unroll
    for (int kt = 0; kt < 2; ++kt){
      const int kby = kt*64 + (lane >> 4)*16;
      short8 afr[4], bfr[4];
      #pragma unroll
      for (int mt = 0; mt < 4; ++mt){
        int row = mt*16 + (lane & 15);
        afr[mt] = *(const short8*)(Abuf + ((row*128 + kby) ^ ((row & 7) << 4)));
      }
      #pragma unroll
      for (int nt = 0; nt < 4; ++nt){
        int col = w*64 + nt*16 + (lane & 15);
        bfr[nt] = *(const short8*)(Bbuf + ((col*128 + kby) ^ ((col & 7) << 4)));
      }
      #pragma unroll
      for (int mt = 0; mt < 4; ++mt){
        #pragma unroll
        for (int nt = 0; nt < 4; ++nt){
          acc[mt][nt] = __builtin_amdgcn_mfma_f32_16x16x32_bf16(afr[mt], bfr[nt], acc[mt][nt], 0, 0, 0);
        }
      }
    }
  }
  float* dst = partials + (size_t)blockIdx.y * (4096*256);
  #pragma unroll
  for (int mt = 0; mt < 4; ++mt){
    #pragma unroll
    for (int nt = 0; nt < 4; ++nt){
      #pragma unroll
      for (int i = 0; i < 4; ++i){
        int n = n0 + mt*16 + (lane >> 4)*4 + i;
        int col = w*64 + nt*16 + (lane & 15);
        dst[(size_t)n*256 + col] = acc[mt][nt][i];
      }
    }
  }
}

// ---------------------------------------------------------------------------
// Reduce split-K partials, ev = tanh(.+bc), prob softmax + cost.
// ---------------------------------------------------------------------------
__global__ void __launch_bounds__(256) heads_k(
    const float* __restrict__ partials, const float* __restrict__ bc,
    const float* __restrict__ Wprob, const float* __restrict__ bprob,
    const float* __restrict__ Wasso, const float* __restrict__ basso,
    float* __restrict__ out1, float* __restrict__ out2)
{
  __shared__ float evs[16][257];
  const int tid = threadIdx.x;
  const int nl = tid >> 4, part = tid & 15;
  const int n = blockIdx.x * 16 + nl;
  #pragma unroll
  for (int q = 0; q < 4; ++q){
    const int c = part*16 + q*4;
    f32x4 s = {0.f,0.f,0.f,0.f};
    #pragma unroll
    for (int p = 0; p < 8; ++p){
      s += *(const f32x4*)(partials + (size_t)p*1048576 + (size_t)n*256 + c);
    }
    #pragma unroll
    for (int j = 0; j < 4; ++j) evs[nl][c + j] = tanh_(s[j] + bc[c + j]);
  }
  __syncthreads();
  float s0 = 0.f, s1 = 0.f, s2 = 0.f;
  #pragma unroll
  for (int j = 0; j < 16; ++j){
    int c = part*16 + j;
    float e = evs[nl][c];
    s0 += e * Wprob[c*2];
    s1 += e * Wprob[c*2 + 1];
    s2 += e * Wasso[c];
  }
  s0 += __shfl_xor(s0, 1); s1 += __shfl_xor(s1, 1); s2 += __shfl_xor(s2, 1);
  s0 += __shfl_xor(s0, 2); s1 += __shfl_xor(s1, 2); s2 += __shfl_xor(s2, 2);
  s0 += __shfl_xor(s0, 4); s1 += __shfl_xor(s1, 4); s2 += __shfl_xor(s2, 4);
  s0 += __shfl_xor(s0, 8); s1 += __shfl_xor(s1, 8); s2 += __shfl_xor(s2, 8);
  if (part == 0){
    float a0 = s0 + bprob[0], a1 = s1 + bprob[1];
    float m = fmaxf(a0, a1);
    float e0 = __expf(a0 - m), e1 = __expf(a1 - m);
    float inv = 1.f / (e0 + e1);
    out2[(size_t)n*96 + 0] = e0 * inv;
    out2[(size_t)n*96 + 1] = e1 * inv;
    out1[(size_t)n*96 + 0] = s2 + basso[0];
  }
}

// ---------------------------------------------------------------------------
extern "C" void kernel_launch(void* const* d_in, const int* in_sizes, int n_in,
                              void* d_out, int out_size, void* d_ws, size_t ws_size,
                              hipStream_t stream)
{
  (void)in_sizes; (void)n_in; (void)ws_size;
  const float* inputs = (const float*)d_in[0];
  const float* Wi     = (const float*)d_in[1];
  const float* Wh     = (const float*)d_in[2];
  const float* bl     = (const float*)d_in[3];
  const float* Wp     = (const float*)d_in[4];
  const float* bp     = (const float*)d_in[5];
  const float* W1     = (const float*)d_in[6];
  const float* b1     = (const float*)d_in[7];
  const float* W2     = (const float*)d_in[8];
  const float* b2     = (const float*)d_in[9];
  const float* Wc     = (const float*)d_in[10];
  const float* bc     = (const float*)d_in[11];
  const float* Wprob  = (const float*)d_in[12];
  const float* bprob  = (const float*)d_in[13];
  const float* Wasso  = (const float*)d_in[14];
  const float* basso  = (const float*)d_in[15];
  float* out = (float*)d_out;

  // workspace layout (~152 MB)
  char* ws = (char*)d_ws;
  unsigned short* concat = (unsigned short*)ws;                 // [4096][14336] bf16 swizzled
  unsigned short* WhT    = (unsigned short*)(ws + 117440512);   // [512][128] bf16
  unsigned short* W2T    = (unsigned short*)(ws + 117571584);   // [256][256] bf16
  unsigned short* WcT    = (unsigned short*)(ws + 117702656);   // [256][14336] bf16 swizzled
  float*          parts  = (float*)(ws + 125042688);            // [8][4096][256] f32

  hipMemsetAsync(d_out, 0, (size_t)out_size * sizeof(float), stream);
  dim3 blk(256);
  transpose_bf16_k<false><<<dim3(16, 4),  blk, 0, stream>>>(Wh, WhT, 128, 512);
  transpose_bf16_k<false><<<dim3(8, 8),   blk, 0, stream>>>(W2, W2T, 256, 256);
  transpose_bf16_k<true ><<<dim3(8, 448), blk, 0, stream>>>(Wc, WcT, 14336, 256);
  copy_out3_k<<<384, blk, 0, stream>>>(inputs, out + 3*393216);
  lstm_k<<<256, dim3(512), 0, stream>>>(inputs, Wi, WhT, bl, Wp, bp, concat, out);
  t1t2_k<<<1536, blk, 0, stream>>>(out, W1, b1, W2T, b2, concat);
  ev_k<<<dim3(64, 8), blk, 0, stream>>>(concat, WcT, parts);
  heads_k<<<256, blk, 0, stream>>>(parts, bc, Wprob, bprob, Wasso, basso,
                                   out + 393216, out + 2*393216);
}

// Round 3
// 360.507 us; speedup vs baseline: 1.1483x; 1.0295x over previous
//
#include <hip/hip_runtime.h>
#include <stdint.h>

typedef float  f32x4  __attribute__((ext_vector_type(4)));
typedef short  short8 __attribute__((ext_vector_type(8)));

#define DEV __device__ __forceinline__

DEV unsigned short f2bf(float x){
  union { float f; unsigned u; } v; v.f = x;
  unsigned r = v.u + 0x7fffu + ((v.u >> 16) & 1u);   // RNE
  return (unsigned short)(r >> 16);
}
DEV float bf2f(unsigned short u){
  union { unsigned u; float f; } v; v.u = ((unsigned)u) << 16;
  return v.f;
}
DEV float sig_(float x){ return 1.f/(1.f + __expf(-x)); }
DEV float tanh_(float x){ return 1.f - 2.f/(__expf(2.f*x) + 1.f); }

// ---------------------------------------------------------------------------
// Transpose fp32 [R][C] -> bf16 [C][R]; optional 8-block XOR swizzle on k-dim
// ---------------------------------------------------------------------------
template<bool SWZ>
__global__ void __launch_bounds__(256) transpose_bf16_k(const float* __restrict__ src,
    unsigned short* __restrict__ dst, int R, int C)
{
  __shared__ float tile[32][33];
  const int tx = threadIdx.x & 31, ty = threadIdx.x >> 5;
  const int c0 = blockIdx.x * 32, r0 = blockIdx.y * 32;
  #pragma unroll
  for (int m = 0; m < 4; ++m){
    int r = ty + m*8;
    tile[r][tx] = src[(size_t)(r0 + r) * C + (c0 + tx)];
  }
  __syncthreads();
  #pragma unroll
  for (int m = 0; m < 4; ++m){
    int cc = c0 + ty + m*8;
    int k  = r0 + tx;
    int k2 = SWZ ? (k ^ ((cc & 7) << 3)) : k;
    dst[(size_t)cc * R + k2] = f2bf(tile[tx][ty + m*8]);
  }
}

// ---------------------------------------------------------------------------
// out[3] = inputs[:,:,:,16:,:]
// ---------------------------------------------------------------------------
__global__ void __launch_bounds__(256) copy_out3_k(const float* __restrict__ in,
                                                   float* __restrict__ out3)
{
  int i = blockIdx.x * 256 + threadIdx.x;        // 98304 float4s
  int n = i / 24, q = i - n*24;
  f32x4 v = *(const f32x4*)(in + (size_t)n*128 + 32 + q*4);
  *(f32x4*)(out3 + (size_t)n*96 + q*4) = v;
}

// ---------------------------------------------------------------------------
// LSTM warm-up + autoregressive rollout. v3:
//  - single barrier per step; NOTHING global inside the loop (no vmcnt drain
//    at the barrier): warm-up h staged in 64KB LDS, preds in 6KB LDS, both
//    flushed coalesced after the loop.
//  - pred(t-1) computed by EVERY wave redundantly via 4 extra MFMAs against a
//    zero-padded Wp B-fragment (cols 0,1 = Wp), using the same afr fragments
//    as the gate MFMAs; 2-lane shfl broadcast. No wave-0 special path.
//  - ping-pong hbuf (read h(t-1) from buf[(t+1)&1], write h(t) to buf[t&1])
//    removes the read/write hazard without a second barrier.
//  - hbuf layout [kgroup(16)][row(16)][16B]: ds_read_b128 conflict-free.
// ---------------------------------------------------------------------------
__global__ void __launch_bounds__(512, 2) lstm_k(
    const float* __restrict__ inputs, const float* __restrict__ Wi,
    const unsigned short* __restrict__ WhT, const float* __restrict__ bl,
    const float* __restrict__ Wp, const float* __restrict__ bp,
    unsigned short* __restrict__ concat, float* __restrict__ out0)
{
  __shared__ __align__(16) unsigned char hbuf[2*16*16*16];   // ping-pong [kgrp][row][16B]
  __shared__ __align__(16) unsigned char hwu[16*16*256];     // warm-up h [t][s][256B]
  __shared__ float predb[48][16][2];                         // AR preds
  __shared__ float xwu[16][33];                              // warm-up inputs (padded)
  const int tid = threadIdx.x, lane = tid & 63, w = tid >> 6;
  const int n0 = blockIdx.x * 16;
  const int col = lane & 15;                 // MFMA col / unit-within-slice
  const int u = w*16 + col;                  // unit owned by this thread
  const int rbase = (lane >> 4) * 4;         // rows rbase..rbase+3

  { int s = tid >> 5, e = tid & 31;
    xwu[s][e] = inputs[(size_t)(n0 + s)*128 + e]; }

  // Wh B-frags: gate g, col = g*128 + u (WhT = [512 cols][128 k])
  short8 bfrag[4][4];
  #pragma unroll
  for (int g = 0; g < 4; ++g){
    const unsigned short* p = WhT + (size_t)(g*128 + u) * 128;
    #pragma unroll
    for (int kt = 0; kt < 4; ++kt)
      bfrag[g][kt] = *(const short8*)(p + kt*32 + (lane >> 4)*8);
  }
  // Wp B-frag: cols 0,1 = Wp[:,col], other cols zero
  short8 wpf[4];
  #pragma unroll
  for (int kt = 0; kt < 4; ++kt){
    short8 v;
    #pragma unroll
    for (int j = 0; j < 8; ++j){
      int k = kt*32 + (lane >> 4)*8 + j;
      v[j] = (col < 2) ? (short)f2bf(Wp[k*2 + col]) : (short)0;
    }
    wpf[kt] = v;
  }
  float wi0[4], wi1[4], bb[4];
  #pragma unroll
  for (int g = 0; g < 4; ++g){
    int c = g*128 + u;
    wi0[g] = Wi[c]; wi1[g] = Wi[512 + c]; bb[g] = bl[c];
  }
  const float bpv = (col == 0) ? bp[0] : ((col == 1) ? bp[1] : 0.f);
  float cst[4] = {0.f, 0.f, 0.f, 0.f};
  __syncthreads();

  #pragma unroll 1
  for (int t = 0; t < 64; ++t){
    const unsigned char* rd = hbuf + ((t + 1) & 1) * 4096;
    unsigned char*       wr = hbuf + (t & 1) * 4096;
    short8 afr[4];
    if (t > 0){
      #pragma unroll
      for (int kt = 0; kt < 4; ++kt)
        afr[kt] = *(const short8*)(rd + (kt*4 + (lane >> 4))*256 + col*16);
    }
    float x0[4], x1[4];
    if (t < 16){
      #pragma unroll
      for (int i = 0; i < 4; ++i){
        x0[i] = xwu[rbase + i][t*2]; x1[i] = xwu[rbase + i][t*2 + 1];
      }
    } else {
      f32x4 pacc = {0.f, 0.f, 0.f, 0.f};
      #pragma unroll
      for (int kt = 0; kt < 4; ++kt)
        pacc = __builtin_amdgcn_mfma_f32_16x16x32_bf16(afr[kt], wpf[kt], pacc, 0, 0, 0);
      float val[4];
      #pragma unroll
      for (int i = 0; i < 4; ++i) val[i] = tanh_(pacc[i] + bpv);
      #pragma unroll
      for (int i = 0; i < 4; ++i){
        x0[i] = __shfl(val[i], (lane & 48) | 0, 64);
        x1[i] = __shfl(val[i], (lane & 48) | 1, 64);
      }
      if (w == 0 && col < 2 && t >= 17){
        #pragma unroll
        for (int i = 0; i < 4; ++i) predb[t - 17][rbase + i][col] = val[i];
      }
    }
    f32x4 acc[4];
    #pragma unroll
    for (int g = 0; g < 4; ++g) acc[g] = (f32x4){bb[g], bb[g], bb[g], bb[g]};
    if (t > 0){
      #pragma unroll
      for (int kt = 0; kt < 4; ++kt){
        #pragma unroll
        for (int g = 0; g < 4; ++g)
          acc[g] = __builtin_amdgcn_mfma_f32_16x16x32_bf16(afr[kt], bfrag[g][kt], acc[g], 0, 0, 0);
      }
    }
    #pragma unroll
    for (int i = 0; i < 4; ++i){
      float z0 = acc[0][i] + x0[i]*wi0[0] + x1[i]*wi1[0];
      float z1 = acc[1][i] + x0[i]*wi0[1] + x1[i]*wi1[1];
      float z2 = acc[2][i] + x0[i]*wi0[2] + x1[i]*wi1[2];
      float z3 = acc[3][i] + x0[i]*wi0[3] + x1[i]*wi1[3];
      float iv = sig_(z0), fv = sig_(z1), gv = tanh_(z2), ov = sig_(z3);
      float c = fv*cst[i] + iv*gv;
      cst[i] = c;
      float hf = ov * tanh_(c);
      unsigned short hb = f2bf(hf);
      int r = rbase + i;
      *(unsigned short*)(wr + (u >> 3)*256 + r*16 + (u & 7)*2) = hb;
      if (t < 16)
        *(unsigned short*)(hwu + t*4096 + r*256 + u*2) = hb;
    }
    __syncthreads();
  }
  // epilogue: pred(63) from h(63) (buffer 63&1 = 1)
  {
    const unsigned char* rd = hbuf + 4096;
    short8 afr[4];
    #pragma unroll
    for (int kt = 0; kt < 4; ++kt)
      afr[kt] = *(const short8*)(rd + (kt*4 + (lane >> 4))*256 + col*16);
    f32x4 pacc = {0.f, 0.f, 0.f, 0.f};
    #pragma unroll
    for (int kt = 0; kt < 4; ++kt)
      pacc = __builtin_amdgcn_mfma_f32_16x16x32_bf16(afr[kt], wpf[kt], pacc, 0, 0, 0);
    if (w == 0 && col < 2){
      #pragma unroll
      for (int i = 0; i < 4; ++i) predb[47][rbase + i][col] = tanh_(pacc[i] + bpv);
    }
  }
  __syncthreads();
  // flush warm-up h -> concat (pre-swizzled for ev_k's linear staging)
  for (int idx = tid; idx < 4096; idx += 512){
    int t = idx >> 8, s = (idx >> 4) & 15, j = idx & 15;
    short8 v = *(const short8*)(hwu + t*4096 + s*256 + j*16);
    *(short8*)((unsigned char*)concat + (size_t)(n0 + s)*28672
        + ((unsigned)(t*256 + j*16) ^ ((s & 7) << 4))) = v;
  }
  // flush preds -> out0 (coalesced)
  for (int idx = tid; idx < 1536; idx += 512){
    int s = idx / 96, r = idx - s*96;
    out0[(size_t)(n0 + s)*96 + r] = predb[r >> 1][s][r & 1];
  }
}

// ---------------------------------------------------------------------------
// t1 = tanh(preds@W1+b1); t2 = tanh(t1@W2+b2) -> concat[:, 2048 + t*256 + c]
// ---------------------------------------------------------------------------
__global__ void __launch_bounds__(256) t1t2_k(
    const float* __restrict__ preds, const float* __restrict__ W1,
    const float* __restrict__ b1, const unsigned short* __restrict__ W2T,
    const float* __restrict__ b2, unsigned short* __restrict__ concat)
{
  __shared__ __align__(16) unsigned char t1buf[16*512];   // bf16 [16][256] swizzled
  const int tid = threadIdx.x, lane = tid & 63, w = tid >> 6;

  short8 bfrag[4][8];
  {
    const int krow = (lane >> 4) * 8;
    #pragma unroll
    for (int nt = 0; nt < 4; ++nt){
      const unsigned short* p = W2T + (size_t)(w*64 + nt*16 + (lane & 15)) * 256;
      #pragma unroll
      for (int kt = 0; kt < 8; ++kt){
        bfrag[nt][kt] = *(const short8*)(p + kt*32 + krow);
      }
    }
  }
  float b2c[4];
  #pragma unroll
  for (int nt = 0; nt < 4; ++nt) b2c[nt] = b2[w*64 + nt*16 + (lane & 15)];
  float w1a[16], w1b[16], b1c[16];
  {
    const int k0 = (tid & 15) * 16;
    #pragma unroll
    for (int j = 0; j < 16; ++j){
      w1a[j] = W1[k0 + j]; w1b[j] = W1[256 + k0 + j]; b1c[j] = b1[k0 + j];
    }
  }
  const int lr = tid >> 4, k0 = (tid & 15) * 16;

  #pragma unroll 1
  for (int rt = 0; rt < 8; ++rt){
    const int r0 = blockIdx.x * 128 + rt * 16;
    {
      const float p0 = preds[(size_t)(r0 + lr)*2 + 0];
      const float p1 = preds[(size_t)(r0 + lr)*2 + 1];
      const int sw = (lr & 7) << 4;
      #pragma unroll
      for (int h = 0; h < 2; ++h){
        short8 t1v;
        #pragma unroll
        for (int j = 0; j < 8; ++j){
          int jj = h*8 + j;
          t1v[j] = (short)f2bf(tanh_(p0*w1a[jj] + p1*w1b[jj] + b1c[jj]));
        }
        *(short8*)(t1buf + ((lr*512 + (k0 + h*8)*2) ^ sw)) = t1v;
      }
    }
    __syncthreads();
    f32x4 acc[4];
    #pragma unroll
    for (int nt = 0; nt < 4; ++nt) acc[nt] = (f32x4){0.f,0.f,0.f,0.f};
    {
      const int row = lane & 15;
      const int sw = (row & 7) << 4;
      #pragma unroll
      for (int kt = 0; kt < 8; ++kt){
        short8 a = *(const short8*)(t1buf + ((row*512 + (kt*32 + (lane>>4)*8)*2) ^ sw));
        #pragma unroll
        for (int nt = 0; nt < 4; ++nt){
          acc[nt] = __builtin_amdgcn_mfma_f32_16x16x32_bf16(a, bfrag[nt][kt], acc[nt], 0, 0, 0);
        }
      }
    }
    #pragma unroll
    for (int nt = 0; nt < 4; ++nt){
      const int col = w*64 + nt*16 + (lane & 15);
      #pragma unroll
      for (int i = 0; i < 4; ++i){
        int m = r0 + (lane >> 4)*4 + i;
        int n = m / 48, tt = m - n*48;
        unsigned short val = f2bf(tanh_(acc[nt][i] + b2c[nt]));
        *(unsigned short*)((unsigned char*)concat + (size_t)n*28672
            + ((unsigned)((2048 + tt*256 + col)*2) ^ ((n & 7) << 4))) = val;
      }
    }
    __syncthreads();
  }
}

// ---------------------------------------------------------------------------
// ev GEMM: [4096 x 14336] @ WcT -> split-K(8) partials [8][4096][256] fp32.
// ---------------------------------------------------------------------------
__global__ void __launch_bounds__(256) ev_k(
    const unsigned short* __restrict__ concat, const unsigned short* __restrict__ WcT,
    float* __restrict__ partials)
{
  __shared__ __align__(16) unsigned char Abuf[64*128];    // bf16 [64 rows][64 k]
  __shared__ __align__(16) unsigned char Bbuf[256*128];   // bf16 [256 cols][64 k]
  const int tid = threadIdx.x, lane = tid & 63, w = tid >> 6;
  const int n0 = blockIdx.x * 64;
  const int kbase = blockIdx.y * 1792;

  f32x4 acc[4][4];
  #pragma unroll
  for (int mt = 0; mt < 4; ++mt){
    #pragma unroll
    for (int nt = 0; nt < 4; ++nt) acc[mt][nt] = (f32x4){0.f,0.f,0.f,0.f};
  }

  const int aoff = tid * 32;
  const int arow = aoff >> 7;
  const unsigned char* asrc = (const unsigned char*)concat + (size_t)(n0 + arow)*28672 + (aoff & 127);
  const unsigned char* bsrc = (const unsigned char*)WcT + (size_t)tid*28672;

  #pragma unroll 1
  for (int ch = 0; ch < 28; ++ch){
    const int kk2 = (kbase + ch*64) * 2;
    short8 ar0 = *(const short8*)(asrc + kk2);
    short8 ar1 = *(const short8*)(asrc + kk2 + 16);
    short8 br[8];
    #pragma unroll
    for (int kb = 0; kb < 8; ++kb) br[kb] = *(const short8*)(bsrc + kk2 + kb*16);
    __syncthreads();
    *(short8*)(Abuf + aoff)      = ar0;
    *(short8*)(Abuf + aoff + 16) = ar1;
    #pragma unroll
    for (int kb = 0; kb < 8; ++kb) *(short8*)(Bbuf + tid*128 + kb*16) = br[kb];
    __syncthreads();
    #pragma unroll
    for (int kt = 0; kt < 2; ++kt){
      const int kby = kt*64 + (lane >> 4)*16;
      short8 afr[4], bfr[4];
      #pragma unroll
      for (int mt = 0; mt < 4; ++mt){
        int row = mt*16 + (lane & 15);
        afr[mt] = *(const short8*)(Abuf + ((row*128 + kby) ^ ((row & 7) << 4)));
      }
      #pragma unroll
      for (int nt = 0; nt < 4; ++nt){
        int col = w*64 + nt*16 + (lane & 15);
        bfr[nt] = *(const short8*)(Bbuf + ((col*128 + kby) ^ ((col & 7) << 4)));
      }
      #pragma unroll
      for (int mt = 0; mt < 4; ++mt){
        #pragma unroll
        for (int nt = 0; nt < 4; ++nt){
          acc[mt][nt] = __builtin_amdgcn_mfma_f32_16x16x32_bf16(afr[mt], bfr[nt], acc[mt][nt], 0, 0, 0);
        }
      }
    }
  }
  float* dst = partials + (size_t)blockIdx.y * (4096*256);
  #pragma unroll
  for (int mt = 0; mt < 4; ++mt){
    #pragma unroll
    for (int nt = 0; nt < 4; ++nt){
      #pragma unroll
      for (int i = 0; i < 4; ++i){
        int n = n0 + mt*16 + (lane >> 4)*4 + i;
        int col = w*64 + nt*16 + (lane & 15);
        dst[(size_t)n*256 + col] = acc[mt][nt][i];
      }
    }
  }
}

// ---------------------------------------------------------------------------
// Reduce split-K partials, ev = tanh(.+bc), prob softmax + cost.
// ---------------------------------------------------------------------------
__global__ void __launch_bounds__(256) heads_k(
    const float* __restrict__ partials, const float* __restrict__ bc,
    const float* __restrict__ Wprob, const float* __restrict__ bprob,
    const float* __restrict__ Wasso, const float* __restrict__ basso,
    float* __restrict__ out1, float* __restrict__ out2)
{
  __shared__ float evs[16][257];
  const int tid = threadIdx.x;
  const int nl = tid >> 4, part = tid & 15;
  const int n = blockIdx.x * 16 + nl;
  #pragma unroll
  for (int q = 0; q < 4; ++q){
    const int c = part*16 + q*4;
    f32x4 s = {0.f,0.f,0.f,0.f};
    #pragma unroll
    for (int p = 0; p < 8; ++p){
      s += *(const f32x4*)(partials + (size_t)p*1048576 + (size_t)n*256 + c);
    }
    #pragma unroll
    for (int j = 0; j < 4; ++j) evs[nl][c + j] = tanh_(s[j] + bc[c + j]);
  }
  __syncthreads();
  float s0 = 0.f, s1 = 0.f, s2 = 0.f;
  #pragma unroll
  for (int j = 0; j < 16; ++j){
    int c = part*16 + j;
    float e = evs[nl][c];
    s0 += e * Wprob[c*2];
    s1 += e * Wprob[c*2 + 1];
    s2 += e * Wasso[c];
  }
  s0 += __shfl_xor(s0, 1); s1 += __shfl_xor(s1, 1); s2 += __shfl_xor(s2, 1);
  s0 += __shfl_xor(s0, 2); s1 += __shfl_xor(s1, 2); s2 += __shfl_xor(s2, 2);
  s0 += __shfl_xor(s0, 4); s1 += __shfl_xor(s1, 4); s2 += __shfl_xor(s2, 4);
  s0 += __shfl_xor(s0, 8); s1 += __shfl_xor(s1, 8); s2 += __shfl_xor(s2, 8);
  if (part == 0){
    float a0 = s0 + bprob[0], a1 = s1 + bprob[1];
    float m = fmaxf(a0, a1);
    float e0 = __expf(a0 - m), e1 = __expf(a1 - m);
    float inv = 1.f / (e0 + e1);
    out2[(size_t)n*96 + 0] = e0 * inv;
    out2[(size_t)n*96 + 1] = e1 * inv;
    out1[(size_t)n*96 + 0] = s2 + basso[0];
  }
}

// ---------------------------------------------------------------------------
extern "C" void kernel_launch(void* const* d_in, const int* in_sizes, int n_in,
                              void* d_out, int out_size, void* d_ws, size_t ws_size,
                              hipStream_t stream)
{
  (void)in_sizes; (void)n_in; (void)ws_size;
  const float* inputs = (const float*)d_in[0];
  const float* Wi     = (const float*)d_in[1];
  const float* Wh     = (const float*)d_in[2];
  const float* bl     = (const float*)d_in[3];
  const float* Wp     = (const float*)d_in[4];
  const float* bp     = (const float*)d_in[5];
  const float* W1     = (const float*)d_in[6];
  const float* b1     = (const float*)d_in[7];
  const float* W2     = (const float*)d_in[8];
  const float* b2     = (const float*)d_in[9];
  const float* Wc     = (const float*)d_in[10];
  const float* bc     = (const float*)d_in[11];
  const float* Wprob  = (const float*)d_in[12];
  const float* bprob  = (const float*)d_in[13];
  const float* Wasso  = (const float*)d_in[14];
  const float* basso  = (const float*)d_in[15];
  float* out = (float*)d_out;

  // workspace layout (~152 MB)
  char* ws = (char*)d_ws;
  unsigned short* concat = (unsigned short*)ws;                 // [4096][14336] bf16 swizzled
  unsigned short* WhT    = (unsigned short*)(ws + 117440512);   // [512][128] bf16
  unsigned short* W2T    = (unsigned short*)(ws + 117571584);   // [256][256] bf16
  unsigned short* WcT    = (unsigned short*)(ws + 117702656);   // [256][14336] bf16 swizzled
  float*          parts  = (float*)(ws + 125042688);            // [8][4096][256] f32

  hipMemsetAsync(d_out, 0, (size_t)out_size * sizeof(float), stream);
  dim3 blk(256);
  transpose_bf16_k<false><<<dim3(16, 4),  blk, 0, stream>>>(Wh, WhT, 128, 512);
  transpose_bf16_k<false><<<dim3(8, 8),   blk, 0, stream>>>(W2, W2T, 256, 256);
  transpose_bf16_k<true ><<<dim3(8, 448), blk, 0, stream>>>(Wc, WcT, 14336, 256);
  copy_out3_k<<<384, blk, 0, stream>>>(inputs, out + 3*393216);
  lstm_k<<<256, dim3(512), 0, stream>>>(inputs, Wi, WhT, bl, Wp, bp, concat, out);
  t1t2_k<<<1536, blk, 0, stream>>>(out, W1, b1, W2T, b2, concat);
  ev_k<<<dim3(64, 8), blk, 0, stream>>>(concat, WcT, parts);
  heads_k<<<256, blk, 0, stream>>>(parts, bc, Wprob, bprob, Wasso, basso,
                                   out + 393216, out + 2*393216);
}